// Round 7
// baseline (883.268 us; speedup 1.0000x reference)
//
#include <hip/hip_runtime.h>
#include <math.h>

// Problem dims (fixed)
#define BB   16
#define SS   2048
#define DIN  256
#define DEMB 512
#define DKQ  512
#define DVV  512

typedef _Float16 f16;
typedef _Float16 half8  __attribute__((ext_vector_type(8)));
typedef _Float16 f16x4  __attribute__((ext_vector_type(4)));
typedef float    f32x4  __attribute__((ext_vector_type(4)));
typedef float    f32x16 __attribute__((ext_vector_type(16)));

#define GLOAD_LDS16(gp, lp)                                                        \
  __builtin_amdgcn_global_load_lds(                                                \
      (const __attribute__((address_space(1))) unsigned int*)(gp),                 \
      (__attribute__((address_space(3))) unsigned int*)(lp), 16, 0, 0)

// V slot permute: decorrelates LDS bank-start across dv rows (2-way max)
__device__ __forceinline__ int vperm(int dv) { return (dv ^ (dv >> 2)) & 3; }

// ---------------------------------------------------------------------------
// Kernel 0: split x (fp32) -> Xh, Xl (fp16 pair, exact to ~2^-22)
// ---------------------------------------------------------------------------
__global__ __launch_bounds__(256) void prep_x(
    const float* __restrict__ x, f16* __restrict__ Xh, f16* __restrict__ Xl)
{
    int idx = blockIdx.x * 256 + threadIdx.x;
    float4 v = ((const float4*)x)[idx];
    f16x4 h, l;
    h.x = (f16)v.x; l.x = (f16)(v.x - (float)h.x);
    h.y = (f16)v.y; l.y = (f16)(v.y - (float)h.y);
    h.z = (f16)v.z; l.z = (f16)(v.z - (float)h.z);
    h.w = (f16)v.w; l.w = (f16)(v.w - (float)h.w);
    ((f16x4*)Xh)[idx] = h;
    ((f16x4*)Xl)[idx] = l;
}

// ---------------------------------------------------------------------------
// Kernel 1: fuse weights W' = W_embed @ W (fp32 math), output TRANSPOSED
// Wth [z][n=512][k=256], f16 high part. Tiled: block = 256 n-cols x 8 m-rows.
// ---------------------------------------------------------------------------
__global__ __launch_bounds__(256) void fuse_weights(
    const float* __restrict__ We, const float* __restrict__ Wk,
    const float* __restrict__ Wq, const float* __restrict__ Wv,
    f16* __restrict__ Wth)
{
    const int n  = blockIdx.x * 256 + threadIdx.x;   // 0..511
    const int m0 = blockIdx.y * 8;                   // 8 m-rows per block
    const int z  = blockIdx.z;
    const float* Wsrc = (z == 0) ? Wk : (z == 1) ? Wq : Wv;

    float acc[8];
#pragma unroll
    for (int j = 0; j < 8; ++j) acc[j] = 0.f;

#pragma unroll 8
    for (int kk = 0; kk < DEMB; ++kk) {
        float wv = Wsrc[kk * 512 + n];
#pragma unroll
        for (int j = 0; j < 8; ++j)
            acc[j] += We[(m0 + j) * DEMB + kk] * wv;
    }
#pragma unroll
    for (int j = 0; j < 8; ++j)
        Wth[(size_t)z * 131072 + n * 256 + m0 + j] = (f16)acc[j];
}

// ---------------------------------------------------------------------------
// Kernel 2 (v4): MFMA projections, 2-term fp16 split (Ah*Bh + Al*Bh).
// STAGING-VOLUME-MINIMAL design (qkv is staging-bound at ~3.3 TB/s across
// R4/R5/R6): tile 256m x FULL 512n, so A and B are each staged exactly once
// per block: 384 blocks x 512 KB = 196 MB total (2.5x less than R5).
// 1024 threads / 16 waves, wave tile 64m x 128n (acc 32 x f32x4 = 128 VGPR).
// K-chunk 32, double-buffered 2 x 64 KB; ONE barrier per chunk (stage c+1 at
// interval top, vmcnt(0) only at the barrier). k-slot XOR swizzle
// (slot = quad ^ (l15>>2)) on both staging source and ds_read: max 2-way
// bank aliasing (free) — fixes R6's 8-way conflict. XCD decode pins each
// m-panel's batch to the attn2-owning XCD. Epilogue in two 256-col passes
// through the freed LDS. Numerics identical to R5/R6.
//   z=0 -> Kh [row][512]; z=1 -> Qh [row][512] PRE-SCALED by log2(e);
//   z=2 -> Vt2 [b][tile(64)][dv(512)][32 keys], slots permuted by vperm(dv)
// ---------------------------------------------------------------------------
#define VAH 0        // A-high: 256 rows x 32 k = 8192 shorts (16 KB)
#define VAL 8192     // A-low
#define VBH 16384    // B: 512 rows x 32 k = 16384 shorts (32 KB)
#define VBUF 32768   // one buffer = 32768 shorts (64 KB); x2 = 128 KB
#define VLDS 67584   // total shorts: max(2*VBUF=65536, epilogue 256*264=67584)

__global__ __launch_bounds__(1024) void qkv_gemm(
    const f16* __restrict__ Xh, const f16* __restrict__ Xl,
    const f16* __restrict__ Wth,
    f16* __restrict__ Kh, f16* __restrict__ Qh, f16* __restrict__ Vt2)
{
    __shared__ __align__(16) short smq[VLDS];   // 135168 B

    const int tid  = threadIdx.x;
    const int lane = tid & 63;
    const int w    = tid >> 6;                   // 0..15
    const int l15  = lane & 15;
    const int quad = lane >> 4;

    // XCD-pinned decode: xcd owns batches {xcd, xcd+8} (matches attn2).
    const int gid = blockIdx.x;                  // 0..383
    const int xcd = gid & 7;
    const int r   = gid >> 3;                    // 0..47
    const int z   = r % 3;
    const int q   = r / 3;                       // 0..15
    const int bb  = xcd + ((q >> 3) << 3);       // batch
    const int m0  = (bb * 8 + (q & 7)) * 256;

    const int wm = (w >> 2) * 64;                // wave m-base: 0,64,128,192
    const int wn = (w & 3) * 128;                // wave n-base: 0,128,256,384

    const f16* Bh = Wth + (size_t)z * 131072;

    // staging: lane -> (srow, sslot) over [16 rows][4 x 16B slots]
    const int srow  = lane >> 2;
    const int sslot = lane & 3;
    const int sk    = (sslot ^ ((srow >> 2) & 3)) * 8;   // pre-swizzled k-offset

    auto stage = [&](int c, int buf) {
        const int k0 = c * 32;
        {   // A: wave stages rows [w*16, +16) of Ah and Al (1 KB each)
            int row = w * 16 + srow;
            GLOAD_LDS16(Xh + (size_t)(m0 + row) * 256 + k0 + sk,
                        smq + buf + VAH + w * 16 * 32);
            GLOAD_LDS16(Xl + (size_t)(m0 + row) * 256 + k0 + sk,
                        smq + buf + VAL + w * 16 * 32);
        }
#pragma unroll
        for (int i = 0; i < 2; ++i) {   // B: rows [w*32, +32)
            int rb = w * 32 + i * 16;
            GLOAD_LDS16(Bh + (size_t)(rb + srow) * 256 + k0 + sk,
                        smq + buf + VBH + rb * 32);
        }
    };

    f32x4 acc[4][8];
#pragma unroll
    for (int i = 0; i < 4; ++i)
#pragma unroll
        for (int jj = 0; jj < 8; ++jj) acc[i][jj] = (f32x4){0.f, 0.f, 0.f, 0.f};

    // ---- prologue: stage chunk 0 into buf0 ----
    stage(0, 0);
    asm volatile("s_waitcnt vmcnt(0)" ::: "memory");
    __builtin_amdgcn_s_barrier();
    __builtin_amdgcn_sched_barrier(0);

    const int ksw = (quad ^ (l15 >> 2)) * 8;     // read-side swizzled k-offset

    for (int c = 0; c < 8; ++c) {
        const int bufc = (c & 1) * VBUF;
        const int bufn = ((c + 1) & 1) * VBUF;

        if (c < 7) stage(c + 1, bufn);           // consumed NEXT interval

        __builtin_amdgcn_s_setprio(1);
        half8 ah[4], al[4], bh[8];
#pragma unroll
        for (int i = 0; i < 4; ++i) {
            ah[i] = *(const half8*)(smq + bufc + VAH + (wm + i * 16 + l15) * 32 + ksw);
            al[i] = *(const half8*)(smq + bufc + VAL + (wm + i * 16 + l15) * 32 + ksw);
        }
#pragma unroll
        for (int ni = 0; ni < 8; ++ni)
            bh[ni] = *(const half8*)(smq + bufc + VBH + (wn + ni * 16 + l15) * 32 + ksw);
#pragma unroll
        for (int mi = 0; mi < 4; ++mi)
#pragma unroll
            for (int ni = 0; ni < 8; ++ni) {
                acc[mi][ni] = __builtin_amdgcn_mfma_f32_16x16x32_f16(ah[mi], bh[ni], acc[mi][ni], 0, 0, 0);
                acc[mi][ni] = __builtin_amdgcn_mfma_f32_16x16x32_f16(al[mi], bh[ni], acc[mi][ni], 0, 0, 0);
            }
        __builtin_amdgcn_s_setprio(0);

        asm volatile("s_waitcnt vmcnt(0) lgkmcnt(0)" ::: "memory");
        __builtin_amdgcn_s_barrier();
        __builtin_amdgcn_sched_barrier(0);
    }

    // ---- epilogue: two 256-col passes through LDS (stride 264 shorts) ----
    if (z < 2) {
        const float qsc = (z == 1) ? 1.44269504f : 1.0f;
        f16* Out = (z == 0) ? Kh : Qh;
        const int cg = tid & 31, rt = tid >> 5;
        for (int ph = 0; ph < 2; ++ph) {
            if (((w >> 1) & 1) == ph) {
                const int nloc = (w & 1) * 128;
#pragma unroll
                for (int mi = 0; mi < 4; ++mi)
#pragma unroll
                    for (int ni = 0; ni < 8; ++ni)
#pragma unroll
                        for (int rr = 0; rr < 4; ++rr)
                            *(f16*)(smq + (wm + mi * 16 + quad * 4 + rr) * 264 + nloc + ni * 16 + l15) =
                                (f16)(acc[mi][ni][rr] * qsc);
            }
            __syncthreads();
#pragma unroll
            for (int jj = 0; jj < 8; ++jj) {
                int row = jj * 32 + rt;
                half8 v = *(const half8*)(smq + row * 264 + cg * 8);
                *(half8*)&Out[(size_t)(m0 + row) * 512 + ph * 256 + cg * 8] = v;
            }
            __syncthreads();
        }
    } else {
        // transpose: LDS [dv_local 256][key_local 256], stride 264
        const int kb0 = m0 & 2047;
        const int cg = tid & 31, rt = tid >> 5;
        for (int ph = 0; ph < 2; ++ph) {
            if (((w >> 1) & 1) == ph) {
                const int dvb = (w & 1) * 128;
#pragma unroll
                for (int mi = 0; mi < 4; ++mi)
#pragma unroll
                    for (int ni = 0; ni < 8; ++ni)
#pragma unroll
                        for (int rr = 0; rr < 4; ++rr)
                            *(f16*)(smq + (dvb + ni * 16 + l15) * 264 + wm + mi * 16 + quad * 4 + rr) =
                                (f16)acc[mi][ni][rr];
            }
            __syncthreads();
#pragma unroll
            for (int jj = 0; jj < 8; ++jj) {
                int dvl = jj * 32 + rt;              // 0..255
                int dv  = ph * 256 + dvl;
                half8 v = *(const half8*)(smq + dvl * 264 + cg * 8);
                int tt = (kb0 >> 5) + (cg >> 2);     // key tile
                int s  = (cg & 3) ^ vperm(dv);       // permuted 16B slot
                *(half8*)&Vt2[(((size_t)bb * 64 + tt) * 512 + dv) * 32 + s * 8] = v;
            }
            __syncthreads();
        }
    }
}

// ---------------------------------------------------------------------------
// Kernel 3: MFMA flash attention — ONE barrier per tile (R3, verified 222us),
// SWAPPED-OPERAND scores + lane-local softmax. UNCHANGED.
// ---------------------------------------------------------------------------
#define LKA 0        // K buf0: 32 keys x 512 d   = 16384 shorts
#define LKB 16384    // K buf1
#define LVA 32768    // V buf0: 512 dv x 32 keys  = 16384 shorts
#define LVB 49152    // V buf1
#define LPA 65536    // P buf0: 128 q x stride 40 =  5120 shorts
#define LPB 70656    // P buf1
#define LAA 75776    // alpha buf0/buf1: 2 x 128 floats = 512 shorts
#define LLL 76288    // l[128] floats             =   256 shorts
#define LFA 76544    // flags buf0/buf1: 2 x 8 ints = 32 shorts
#define LTOT 76576   // 153152 bytes (< 160 KiB)

#define THR_L2 11.5416f   // defer-max threshold: 8 nats in log2 units

__global__ __launch_bounds__(512, 2) void attn2(
    const f16* __restrict__ Qh, const f16* __restrict__ Kh,
    const f16* __restrict__ Vt2, float* __restrict__ Y)
{
    __shared__ __align__(16) short sm[LTOT];

    const int tid  = threadIdx.x;
    const int lane = tid & 63;
    const int w    = tid >> 6;                    // 0..7
    // XCD-aware decode: xcd = gid&7; b = (gid&7) + 8*(gid>>7); q0 = ((gid>>3)&15)*128
    const int gid  = blockIdx.x;
    const int b    = (gid & 7) + ((gid >> 7) << 3);
    const int q0   = ((gid >> 3) & 15) << 7;
    const int l15  = lane & 15;
    const int quad = lane >> 4;
    const int l31  = lane & 31;
    const int lhi  = lane >> 5;
    const int qquad = w >> 1, dvhalf = w & 1;     // PV mapping: 4 q-quads x 2 dv-halves

    const f16* Khb  = Kh  + (size_t)b * SS * 512;
    const f16* Vt2b = Vt2 + (size_t)b * 64 * 512 * 32;

    // ---- Q fragments (resident): wave w, q rows q0+16w .. +15 ----
    half8 qh[16];
    {
        const half8* qhp = (const half8*)(Qh + ((size_t)(b * SS + q0 + w * 16 + l15)) * 512);
#pragma unroll
        for (int ks = 0; ks < 16; ++ks) qh[ks] = qhp[ks * 4 + quad];
    }

    f32x16 O[8];
#pragma unroll
    for (int n = 0; n < 8; ++n)
#pragma unroll
        for (int r = 0; r < 16; ++r) O[n][r] = 0.f;

    float m_pr = -1e30f;   // running max, log2 domain (per lane's q row)
    float l_r  = 0.f;      // running denom (per lane's q row)

    // 8 waves x 4 instrs = 32 KB per tile for each of K and V
    auto stage_K = [&](int t, int lk) {
        const int kb = t * 32;
#pragma unroll
        for (int i = 0; i < 4; ++i) {
            int key = w * 4 + i;
            const f16* g = Khb + ((size_t)(kb + key)) * 512 + ((lane ^ (key & 15)) << 3);
            GLOAD_LDS16(g, sm + lk + key * 512);
        }
    };
    auto stage_V = [&](int t, int lv) {
        const f16* gbase = Vt2b + (size_t)t * 16384 + lane * 8;
#pragma unroll
        for (int i = 0; i < 4; ++i) {
            int off = (w * 4 + i) * 512;
            GLOAD_LDS16(gbase + off, sm + lv + off);
        }
    };

    // ---- PV(tp): rescale O by alpha(tp) then O += P(tp) * V(tp) ----
    auto do_pv = [&](int LPp, int LVp, const float* ap, const int* fp) {
        if (fp[2 * qquad] | fp[2 * qquad + 1]) {
            float av[16];
#pragma unroll
            for (int r = 0; r < 16; ++r) {
                int row = (r & 3) + ((r >> 2) << 3) + (lhi << 2);
                av[r] = ap[qquad * 32 + row];
            }
#pragma unroll
            for (int n = 0; n < 8; ++n)
#pragma unroll
                for (int r = 0; r < 16; ++r) O[n][r] *= av[r];
        }
        half8 pA[2];
#pragma unroll
        for (int ks = 0; ks < 2; ++ks) {
            int q  = qquad * 32 + l31;
            int uk = ks * 2 + lhi;
            pA[ks] = *(const half8*)(sm + LPp + q * 40 + uk * 8);
        }
#pragma unroll
        for (int ks = 0; ks < 2; ++ks) {
#pragma unroll
            for (int n = 0; n < 8; ++n) {
                int dv = dvhalf * 256 + n * 32 + l31;
                int uk = ks * 2 + lhi;
                half8 bf = *(const half8*)(sm + LVp + dv * 32 + ((uk ^ vperm(dv)) << 3));
                O[n] = __builtin_amdgcn_mfma_f32_32x32x16_f16(pA[ks], bf, O[n], 0, 0, 0);
            }
        }
    };

    // ---- prologue: stage K(0) into buf0, sync ----
    stage_K(0, LKA);
    asm volatile("s_waitcnt vmcnt(0)" ::: "memory");
    __builtin_amdgcn_s_barrier();
    __builtin_amdgcn_sched_barrier(0);

    for (int t = 0; t < 64; ++t) {
        const int cur = t & 1;
        const int prv = cur ^ 1;
        const int LKc = LKA + cur * 16384;   // K(t)
        const int LKn = LKA + prv * 16384;   // K(t+1) dest
        const int LVc = LVA + cur * 16384;   // V(t) dest
        const int LVp = LVA + prv * 16384;   // V(t-1)
        const int LPc = LPA + cur * 5120;    // P(t) dest
        const int LPp = LPA + prv * 5120;    // P(t-1)
        float* aw = (float*)(sm + LAA + cur * 256);
        const float* ap = (const float*)(sm + LAA + prv * 256);
        int* fw = (int*)(sm + LFA + cur * 16);
        const int* fp = (const int*)(sm + LFA + prv * 16);

        // prefetch: K(t+1) and V(t); both consumed NEXT interval
        if (t + 1 < 64) stage_K(t + 1, LKn);
        stage_V(t, LVc);

        __builtin_amdgcn_s_setprio(1);
        // ---- PV(t-1) ----
        if (t > 0) do_pv(LPp, LVp, ap, fp);

        // ---- scores(t), SWAPPED: S^T = K * Q^T (16x16x32) ----
        f32x4 S[2];
        S[0] = (f32x4){0.f, 0.f, 0.f, 0.f};
        S[1] = (f32x4){0.f, 0.f, 0.f, 0.f};
#pragma unroll
        for (int ks = 0; ks < 16; ++ks) {
#pragma unroll
            for (int n = 0; n < 2; ++n) {
                int key = n * 16 + l15;
                int ud  = ks * 4 + quad;
                half8 bf = *(const half8*)(sm + LKc + key * 512 + ((ud ^ l15) << 3));
                S[n] = __builtin_amdgcn_mfma_f32_16x16x32_f16(bf, qh[ks], S[n], 0, 0, 0);
            }
        }
        __builtin_amdgcn_s_setprio(0);

        // ---- lane-local online softmax (log2 domain), defer-max ----
        float mx = fmaxf(fmaxf(fmaxf(S[0][0], S[0][1]), fmaxf(S[0][2], S[0][3])),
                         fmaxf(fmaxf(S[1][0], S[1][1]), fmaxf(S[1][2], S[1][3])));
        mx = fmaxf(mx, __shfl_xor(mx, 16, 64));
        mx = fmaxf(mx, __shfl_xor(mx, 32, 64));
        bool up  = mx > m_pr + THR_L2;          // defer small max growth
        float mn = up ? mx : m_pr;
        float al = up ? __builtin_amdgcn_exp2f(m_pr - mn) : 1.0f;
        m_pr = mn;

        float p0 = __builtin_amdgcn_exp2f(S[0][0] - mn);
        float p1 = __builtin_amdgcn_exp2f(S[0][1] - mn);
        float p2 = __builtin_amdgcn_exp2f(S[0][2] - mn);
        float p3 = __builtin_amdgcn_exp2f(S[0][3] - mn);
        float p4 = __builtin_amdgcn_exp2f(S[1][0] - mn);
        float p5 = __builtin_amdgcn_exp2f(S[1][1] - mn);
        float p6 = __builtin_amdgcn_exp2f(S[1][2] - mn);
        float p7 = __builtin_amdgcn_exp2f(S[1][3] - mn);
        float sum = ((p0 + p1) + (p2 + p3)) + ((p4 + p5) + (p6 + p7));
        sum += __shfl_xor(sum, 16, 64);
        sum += __shfl_xor(sum, 32, 64);
        l_r = l_r * al + sum;

        {
            int q = w * 16 + l15;
            f16x4 lo, hi;
            lo.x = (f16)p0; lo.y = (f16)p1; lo.z = (f16)p2; lo.w = (f16)p3;
            hi.x = (f16)p4; hi.y = (f16)p5; hi.z = (f16)p6; hi.w = (f16)p7;
            *(f16x4*)(sm + LPc + q * 40 + quad * 4)      = lo;  // keys quad*4..+3
            *(f16x4*)(sm + LPc + q * 40 + 16 + quad * 4) = hi;  // keys 16+quad*4..+3
        }

        unsigned long long bm = __ballot(up);
        if (lane == 0) fw[w] = (bm != 0ULL) ? 1 : 0;
        if (quad == 0) aw[w * 16 + l15] = al;

        // ---- single barrier: P/alpha/flags(t) visible; K(t+1)/V(t) landed ----
        asm volatile("s_waitcnt vmcnt(0) lgkmcnt(0)" ::: "memory");
        __builtin_amdgcn_s_barrier();
        __builtin_amdgcn_sched_barrier(0);
    }

    // ---- final PV(63) (buffers at parity of t=63 -> cur=1) ----
    do_pv(LPA + 5120, LVA + 16384,
          (const float*)(sm + LAA + 256), (const int*)(sm + LFA + 16));

    // ---- epilogue: O /= l, store ----
    float* lptr = (float*)(sm + LLL);
    if (quad == 0) lptr[w * 16 + l15] = l_r;
    __syncthreads();
    float linv[16];
#pragma unroll
    for (int r = 0; r < 16; ++r) {
        int row = (r & 3) + ((r >> 2) << 3) + (lhi << 2);
        linv[r] = 1.0f / lptr[qquad * 32 + row];
    }
#pragma unroll
    for (int n = 0; n < 8; ++n) {
#pragma unroll
        for (int r = 0; r < 16; ++r) {
            int row = (r & 3) + ((r >> 2) << 3) + (lhi << 2);
            Y[((size_t)(b * SS + q0 + qquad * 32 + row)) * 512 + dvhalf * 256 + n * 32 + l31] =
                O[n][r] * linv[r];
        }
    }
}

// ---------------------------------------------------------------------------
// Host launcher
// ---------------------------------------------------------------------------
extern "C" void kernel_launch(void* const* d_in, const int* in_sizes, int n_in,
                              void* d_out, int out_size, void* d_ws, size_t ws_size,
                              hipStream_t stream)
{
    const float* x  = (const float*)d_in[0];
    const float* We = (const float*)d_in[1];
    const float* Wk = (const float*)d_in[2];
    const float* Wq = (const float*)d_in[3];
    const float* Wv = (const float*)d_in[4];
    float* out = (float*)d_out;

    const size_t WSZ = 3 * 256 * 512;          // 393216
    const size_t XSZ = (size_t)BB * SS * DIN;  // 8388608
    const size_t MSZ = (size_t)BB * SS * 512;  // 16777216

    f16* Wth = (f16*)d_ws;
    f16* Wtl = Wth + WSZ;                      // (unused slot kept for layout)
    f16* Xh  = Wtl + WSZ;
    f16* Xl  = Xh + XSZ;
    f16* Qh  = Xl + XSZ;
    f16* Kh  = Qh + MSZ;
    f16* Vt2 = Kh + MSZ;

    prep_x<<<dim3(XSZ / 4 / 256), dim3(256), 0, stream>>>(x, Xh, Xl);

    fuse_weights<<<dim3(2, 32, 3), dim3(256), 0, stream>>>(We, Wk, Wq, Wv, Wth);

    qkv_gemm<<<dim3(384), dim3(1024), 0, stream>>>(
        Xh, Xl, Wth, Kh, Qh, Vt2);

    attn2<<<dim3(256), dim3(512), 0, stream>>>(Qh, Kh, Vt2, out);
}

// Round 8
// 408.848 us; speedup vs baseline: 2.1604x; 2.1604x over previous
//
#include <hip/hip_runtime.h>
#include <math.h>

// Problem dims (fixed)
#define BB   16
#define SS   2048
#define DIN  256
#define DEMB 512
#define DKQ  512
#define DVV  512

typedef _Float16 f16;
typedef _Float16 half8  __attribute__((ext_vector_type(8)));
typedef _Float16 f16x4  __attribute__((ext_vector_type(4)));
typedef float    f32x4  __attribute__((ext_vector_type(4)));
typedef float    f32x16 __attribute__((ext_vector_type(16)));

#define GLOAD_LDS16(gp, lp)                                                        \
  __builtin_amdgcn_global_load_lds(                                                \
      (const __attribute__((address_space(1))) unsigned int*)(gp),                 \
      (__attribute__((address_space(3))) unsigned int*)(lp), 16, 0, 0)

// V slot permute: decorrelates LDS bank-start across dv rows (2-way max)
__device__ __forceinline__ int vperm(int dv) { return (dv ^ (dv >> 2)) & 3; }

// ---------------------------------------------------------------------------
// Kernel 0: split x (fp32) -> Xh, Xl (fp16 pair, exact to ~2^-22)
// ---------------------------------------------------------------------------
__global__ __launch_bounds__(256) void prep_x(
    const float* __restrict__ x, f16* __restrict__ Xh, f16* __restrict__ Xl)
{
    int idx = blockIdx.x * 256 + threadIdx.x;
    float4 v = ((const float4*)x)[idx];
    f16x4 h, l;
    h.x = (f16)v.x; l.x = (f16)(v.x - (float)h.x);
    h.y = (f16)v.y; l.y = (f16)(v.y - (float)h.y);
    h.z = (f16)v.z; l.z = (f16)(v.z - (float)h.z);
    h.w = (f16)v.w; l.w = (f16)(v.w - (float)h.w);
    ((f16x4*)Xh)[idx] = h;
    ((f16x4*)Xl)[idx] = l;
}

// ---------------------------------------------------------------------------
// Kernel 1: fuse weights W' = W_embed @ W (fp32 math), output TRANSPOSED
// Wth [z][n=512][k=256], f16 high part. Tiled: block = 256 n-cols x 8 m-rows.
// ---------------------------------------------------------------------------
__global__ __launch_bounds__(256) void fuse_weights(
    const float* __restrict__ We, const float* __restrict__ Wk,
    const float* __restrict__ Wq, const float* __restrict__ Wv,
    f16* __restrict__ Wth)
{
    const int n  = blockIdx.x * 256 + threadIdx.x;   // 0..511
    const int m0 = blockIdx.y * 8;                   // 8 m-rows per block
    const int z  = blockIdx.z;
    const float* Wsrc = (z == 0) ? Wk : (z == 1) ? Wq : Wv;

    float acc[8];
#pragma unroll
    for (int j = 0; j < 8; ++j) acc[j] = 0.f;

#pragma unroll 8
    for (int kk = 0; kk < DEMB; ++kk) {
        float wv = Wsrc[kk * 512 + n];
#pragma unroll
        for (int j = 0; j < 8; ++j)
            acc[j] += We[(m0 + j) * DEMB + kk] * wv;
    }
#pragma unroll
    for (int j = 0; j < 8; ++j)
        Wth[(size_t)z * 131072 + n * 256 + m0 + j] = (f16)acc[j];
}

// ---------------------------------------------------------------------------
// Kernel 2 (v5): MFMA projections, 2-term fp16 split (Ah*Bh + Al*Bh).
// Staging-minimal AND register-feasible (R7 lesson: wave-area*2 regs must fit
// the occupancy VGPR cap; R7's 64x128 wave tile spilled at the 64-reg default
// cap -> 1.87 GB scratch traffic).
// Tile 256m x 256n, 16 waves (4x4 of 64x64): acc = 64 VGPR, ~105 live < 128
// cap from explicit __launch_bounds__(1024, 4). Staged bytes = 302 MB total
// (vs R5 492 / R6 590). K-chunk 32, dbuf 2x48 KB = 96 KB LDS, single-barrier
// interval schedule (stage c+1 at top, vmcnt(0) only at the barrier).
// Swizzle: source sk=((lane&3)^quad)*8, read ksw=(quad^(l15>>2))*8 —
// bank-balanced (8 acc/bank per b128 = minimum). XCD decode pins each
// m-panel's batch to the attn2-owning XCD. Epilogue: two 128-row passes.
//   z=0 -> Kh [row][512]; z=1 -> Qh [row][512] PRE-SCALED by log2(e);
//   z=2 -> Vt2 [b][tile(64)][dv(512)][32 keys], slots permuted by vperm(dv)
// ---------------------------------------------------------------------------
#define VAH 0        // A-high: 256 rows x 32 k = 8192 shorts (16 KB)
#define VAL 8192     // A-low
#define VBH 16384    // B: 256 rows x 32 k = 8192 shorts
#define VBUF 24576   // one buffer = 24576 shorts (48 KB); x2 = 96 KB
#define VLDS 49152   // 96 KB (epilogue pass uses 128*264=33792 shorts)

__global__ __launch_bounds__(1024, 4) void qkv_gemm(
    const f16* __restrict__ Xh, const f16* __restrict__ Xl,
    const f16* __restrict__ Wth,
    f16* __restrict__ Kh, f16* __restrict__ Qh, f16* __restrict__ Vt2)
{
    __shared__ __align__(16) short smq[VLDS];

    const int tid  = threadIdx.x;
    const int lane = tid & 63;
    const int w    = tid >> 6;                   // 0..15
    const int l15  = lane & 15;
    const int quad = lane >> 4;

    // XCD-pinned decode: xcd owns batches {xcd, xcd+8} (matches attn2).
    const int gid = blockIdx.x;                  // 0..767
    const int xcd = gid & 7;
    const int r   = gid >> 3;                    // 0..95
    const int z   = r % 3;
    const int q   = r / 3;                       // 0..31
    const int nh  = q & 1;
    const int pm  = q >> 1;                      // 0..15
    const int bb  = xcd + ((pm >> 3) << 3);      // batch
    const int m0  = (bb * 8 + (pm & 7)) * 256;
    const int n0  = nh * 256;

    const int wm = (w >> 2) * 64;                // wave m-base: 0,64,128,192
    const int wn = (w & 3) * 64;                 // wave n-base: 0,64,128,192

    const f16* Bh = Wth + (size_t)z * 131072;

    // staging: lane -> row (lane>>2) within wave's 16-row group, slot lane&3
    const int srow = lane >> 2;
    const int sk   = ((lane & 3) ^ quad) * 8;    // pre-swizzled k-offset

    auto stage = [&](int c, int buf) {
        const int k0  = c * 32;
        const int row = w * 16 + srow;
        GLOAD_LDS16(Xh + (size_t)(m0 + row) * 256 + k0 + sk, smq + buf + VAH + w * 512);
        GLOAD_LDS16(Xl + (size_t)(m0 + row) * 256 + k0 + sk, smq + buf + VAL + w * 512);
        GLOAD_LDS16(Bh + (size_t)(n0 + row) * 256 + k0 + sk, smq + buf + VBH + w * 512);
    };

    f32x4 acc[4][4];
#pragma unroll
    for (int i = 0; i < 4; ++i)
#pragma unroll
        for (int jj = 0; jj < 4; ++jj) acc[i][jj] = (f32x4){0.f, 0.f, 0.f, 0.f};

    // ---- prologue: stage chunk 0 into buf0 ----
    stage(0, 0);
    asm volatile("s_waitcnt vmcnt(0)" ::: "memory");
    __builtin_amdgcn_s_barrier();
    __builtin_amdgcn_sched_barrier(0);

    const int ksw = (quad ^ (l15 >> 2)) * 8;     // read-side swizzled k-offset

    for (int c = 0; c < 8; ++c) {
        const int bufc = (c & 1) * VBUF;
        const int bufn = ((c + 1) & 1) * VBUF;

        if (c < 7) stage(c + 1, bufn);           // consumed NEXT interval

        __builtin_amdgcn_s_setprio(1);
        half8 ah[4], al[4];
#pragma unroll
        for (int i = 0; i < 4; ++i) {
            ah[i] = *(const half8*)(smq + bufc + VAH + (wm + i * 16 + l15) * 32 + ksw);
            al[i] = *(const half8*)(smq + bufc + VAL + (wm + i * 16 + l15) * 32 + ksw);
        }
#pragma unroll
        for (int ni = 0; ni < 4; ++ni) {
            half8 bh = *(const half8*)(smq + bufc + VBH + (wn + ni * 16 + l15) * 32 + ksw);
#pragma unroll
            for (int mi = 0; mi < 4; ++mi) {
                acc[mi][ni] = __builtin_amdgcn_mfma_f32_16x16x32_f16(ah[mi], bh, acc[mi][ni], 0, 0, 0);
                acc[mi][ni] = __builtin_amdgcn_mfma_f32_16x16x32_f16(al[mi], bh, acc[mi][ni], 0, 0, 0);
            }
        }
        __builtin_amdgcn_s_setprio(0);

        asm volatile("s_waitcnt vmcnt(0) lgkmcnt(0)" ::: "memory");
        __builtin_amdgcn_s_barrier();
        __builtin_amdgcn_sched_barrier(0);
    }

    // ---- epilogue: two 128-row (or 128-dv) passes, stride 264 shorts ----
    if (z < 2) {
        const float qsc = (z == 1) ? 1.44269504f : 1.0f;
        f16* Out = (z == 0) ? Kh : Qh;
        const int cg = tid & 31, rt = tid >> 5;  // 32 col-groups x 32 row-threads
        for (int ph = 0; ph < 2; ++ph) {
            if ((w >> 3) == ph) {
                const int wml = wm - ph * 128;   // 0 or 64
#pragma unroll
                for (int mi = 0; mi < 4; ++mi)
#pragma unroll
                    for (int ni = 0; ni < 4; ++ni)
#pragma unroll
                        for (int rr = 0; rr < 4; ++rr)
                            *(f16*)(smq + (wml + mi * 16 + quad * 4 + rr) * 264 + wn + ni * 16 + l15) =
                                (f16)(acc[mi][ni][rr] * qsc);
            }
            __syncthreads();
#pragma unroll
            for (int jj = 0; jj < 4; ++jj) {
                int row = jj * 32 + rt;          // 0..127
                half8 v = *(const half8*)(smq + row * 264 + cg * 8);
                *(half8*)&Out[(size_t)(m0 + ph * 128 + row) * 512 + n0 + cg * 8] = v;
            }
            __syncthreads();
        }
    } else {
        // transpose: LDS [dv_local 128][key_local 256], stride 264
        const int kb0 = m0 & 2047;
        const int cg = tid & 31, rt = tid >> 5;  // 32 key-groups x 32 dv-threads
        for (int ph = 0; ph < 2; ++ph) {
            if (((w & 3) >> 1) == ph) {
                const int wnl = wn - ph * 128;   // 0 or 64
#pragma unroll
                for (int mi = 0; mi < 4; ++mi)
#pragma unroll
                    for (int ni = 0; ni < 4; ++ni)
#pragma unroll
                        for (int rr = 0; rr < 4; ++rr)
                            *(f16*)(smq + (wnl + ni * 16 + l15) * 264 + wm + mi * 16 + quad * 4 + rr) =
                                (f16)acc[mi][ni][rr];
            }
            __syncthreads();
#pragma unroll
            for (int jj = 0; jj < 4; ++jj) {
                int dvl = jj * 32 + rt;          // 0..127
                int dv  = n0 + ph * 128 + dvl;
                half8 v = *(const half8*)(smq + dvl * 264 + cg * 8);
                int tt = (kb0 >> 5) + (cg >> 2); // key tile
                int s  = (cg & 3) ^ vperm(dv);   // permuted 16B slot
                *(half8*)&Vt2[(((size_t)bb * 64 + tt) * 512 + dv) * 32 + s * 8] = v;
            }
            __syncthreads();
        }
    }
}

// ---------------------------------------------------------------------------
// Kernel 3: MFMA flash attention — ONE barrier per tile (R3, verified 222us),
// SWAPPED-OPERAND scores + lane-local softmax. UNCHANGED.
// ---------------------------------------------------------------------------
#define LKA 0        // K buf0: 32 keys x 512 d   = 16384 shorts
#define LKB 16384    // K buf1
#define LVA 32768    // V buf0: 512 dv x 32 keys  = 16384 shorts
#define LVB 49152    // V buf1
#define LPA 65536    // P buf0: 128 q x stride 40 =  5120 shorts
#define LPB 70656    // P buf1
#define LAA 75776    // alpha buf0/buf1: 2 x 128 floats = 512 shorts
#define LLL 76288    // l[128] floats             =   256 shorts
#define LFA 76544    // flags buf0/buf1: 2 x 8 ints = 32 shorts
#define LTOT 76576   // 153152 bytes (< 160 KiB)

#define THR_L2 11.5416f   // defer-max threshold: 8 nats in log2 units

__global__ __launch_bounds__(512, 2) void attn2(
    const f16* __restrict__ Qh, const f16* __restrict__ Kh,
    const f16* __restrict__ Vt2, float* __restrict__ Y)
{
    __shared__ __align__(16) short sm[LTOT];

    const int tid  = threadIdx.x;
    const int lane = tid & 63;
    const int w    = tid >> 6;                    // 0..7
    // XCD-aware decode: xcd = gid&7; b = (gid&7) + 8*(gid>>7); q0 = ((gid>>3)&15)*128
    const int gid  = blockIdx.x;
    const int b    = (gid & 7) + ((gid >> 7) << 3);
    const int q0   = ((gid >> 3) & 15) << 7;
    const int l15  = lane & 15;
    const int quad = lane >> 4;
    const int l31  = lane & 31;
    const int lhi  = lane >> 5;
    const int qquad = w >> 1, dvhalf = w & 1;     // PV mapping: 4 q-quads x 2 dv-halves

    const f16* Khb  = Kh  + (size_t)b * SS * 512;
    const f16* Vt2b = Vt2 + (size_t)b * 64 * 512 * 32;

    // ---- Q fragments (resident): wave w, q rows q0+16w .. +15 ----
    half8 qh[16];
    {
        const half8* qhp = (const half8*)(Qh + ((size_t)(b * SS + q0 + w * 16 + l15)) * 512);
#pragma unroll
        for (int ks = 0; ks < 16; ++ks) qh[ks] = qhp[ks * 4 + quad];
    }

    f32x16 O[8];
#pragma unroll
    for (int n = 0; n < 8; ++n)
#pragma unroll
        for (int r = 0; r < 16; ++r) O[n][r] = 0.f;

    float m_pr = -1e30f;   // running max, log2 domain (per lane's q row)
    float l_r  = 0.f;      // running denom (per lane's q row)

    // 8 waves x 4 instrs = 32 KB per tile for each of K and V
    auto stage_K = [&](int t, int lk) {
        const int kb = t * 32;
#pragma unroll
        for (int i = 0; i < 4; ++i) {
            int key = w * 4 + i;
            const f16* g = Khb + ((size_t)(kb + key)) * 512 + ((lane ^ (key & 15)) << 3);
            GLOAD_LDS16(g, sm + lk + key * 512);
        }
    };
    auto stage_V = [&](int t, int lv) {
        const f16* gbase = Vt2b + (size_t)t * 16384 + lane * 8;
#pragma unroll
        for (int i = 0; i < 4; ++i) {
            int off = (w * 4 + i) * 512;
            GLOAD_LDS16(gbase + off, sm + lv + off);
        }
    };

    // ---- PV(tp): rescale O by alpha(tp) then O += P(tp) * V(tp) ----
    auto do_pv = [&](int LPp, int LVp, const float* ap, const int* fp) {
        if (fp[2 * qquad] | fp[2 * qquad + 1]) {
            float av[16];
#pragma unroll
            for (int r = 0; r < 16; ++r) {
                int row = (r & 3) + ((r >> 2) << 3) + (lhi << 2);
                av[r] = ap[qquad * 32 + row];
            }
#pragma unroll
            for (int n = 0; n < 8; ++n)
#pragma unroll
                for (int r = 0; r < 16; ++r) O[n][r] *= av[r];
        }
        half8 pA[2];
#pragma unroll
        for (int ks = 0; ks < 2; ++ks) {
            int q  = qquad * 32 + l31;
            int uk = ks * 2 + lhi;
            pA[ks] = *(const half8*)(sm + LPp + q * 40 + uk * 8);
        }
#pragma unroll
        for (int ks = 0; ks < 2; ++ks) {
#pragma unroll
            for (int n = 0; n < 8; ++n) {
                int dv = dvhalf * 256 + n * 32 + l31;
                int uk = ks * 2 + lhi;
                half8 bf = *(const half8*)(sm + LVp + dv * 32 + ((uk ^ vperm(dv)) << 3));
                O[n] = __builtin_amdgcn_mfma_f32_32x32x16_f16(pA[ks], bf, O[n], 0, 0, 0);
            }
        }
    };

    // ---- prologue: stage K(0) into buf0, sync ----
    stage_K(0, LKA);
    asm volatile("s_waitcnt vmcnt(0)" ::: "memory");
    __builtin_amdgcn_s_barrier();
    __builtin_amdgcn_sched_barrier(0);

    for (int t = 0; t < 64; ++t) {
        const int cur = t & 1;
        const int prv = cur ^ 1;
        const int LKc = LKA + cur * 16384;   // K(t)
        const int LKn = LKA + prv * 16384;   // K(t+1) dest
        const int LVc = LVA + cur * 16384;   // V(t) dest
        const int LVp = LVA + prv * 16384;   // V(t-1)
        const int LPc = LPA + cur * 5120;    // P(t) dest
        const int LPp = LPA + prv * 5120;    // P(t-1)
        float* aw = (float*)(sm + LAA + cur * 256);
        const float* ap = (const float*)(sm + LAA + prv * 256);
        int* fw = (int*)(sm + LFA + cur * 16);
        const int* fp = (const int*)(sm + LFA + prv * 16);

        // prefetch: K(t+1) and V(t); both consumed NEXT interval
        if (t + 1 < 64) stage_K(t + 1, LKn);
        stage_V(t, LVc);

        __builtin_amdgcn_s_setprio(1);
        // ---- PV(t-1) ----
        if (t > 0) do_pv(LPp, LVp, ap, fp);

        // ---- scores(t), SWAPPED: S^T = K * Q^T (16x16x32) ----
        f32x4 S[2];
        S[0] = (f32x4){0.f, 0.f, 0.f, 0.f};
        S[1] = (f32x4){0.f, 0.f, 0.f, 0.f};
#pragma unroll
        for (int ks = 0; ks < 16; ++ks) {
#pragma unroll
            for (int n = 0; n < 2; ++n) {
                int key = n * 16 + l15;
                int ud  = ks * 4 + quad;
                half8 bf = *(const half8*)(sm + LKc + key * 512 + ((ud ^ l15) << 3));
                S[n] = __builtin_amdgcn_mfma_f32_16x16x32_f16(bf, qh[ks], S[n], 0, 0, 0);
            }
        }
        __builtin_amdgcn_s_setprio(0);

        // ---- lane-local online softmax (log2 domain), defer-max ----
        float mx = fmaxf(fmaxf(fmaxf(S[0][0], S[0][1]), fmaxf(S[0][2], S[0][3])),
                         fmaxf(fmaxf(S[1][0], S[1][1]), fmaxf(S[1][2], S[1][3])));
        mx = fmaxf(mx, __shfl_xor(mx, 16, 64));
        mx = fmaxf(mx, __shfl_xor(mx, 32, 64));
        bool up  = mx > m_pr + THR_L2;          // defer small max growth
        float mn = up ? mx : m_pr;
        float al = up ? __builtin_amdgcn_exp2f(m_pr - mn) : 1.0f;
        m_pr = mn;

        float p0 = __builtin_amdgcn_exp2f(S[0][0] - mn);
        float p1 = __builtin_amdgcn_exp2f(S[0][1] - mn);
        float p2 = __builtin_amdgcn_exp2f(S[0][2] - mn);
        float p3 = __builtin_amdgcn_exp2f(S[0][3] - mn);
        float p4 = __builtin_amdgcn_exp2f(S[1][0] - mn);
        float p5 = __builtin_amdgcn_exp2f(S[1][1] - mn);
        float p6 = __builtin_amdgcn_exp2f(S[1][2] - mn);
        float p7 = __builtin_amdgcn_exp2f(S[1][3] - mn);
        float sum = ((p0 + p1) + (p2 + p3)) + ((p4 + p5) + (p6 + p7));
        sum += __shfl_xor(sum, 16, 64);
        sum += __shfl_xor(sum, 32, 64);
        l_r = l_r * al + sum;

        {
            int q = w * 16 + l15;
            f16x4 lo, hi;
            lo.x = (f16)p0; lo.y = (f16)p1; lo.z = (f16)p2; lo.w = (f16)p3;
            hi.x = (f16)p4; hi.y = (f16)p5; hi.z = (f16)p6; hi.w = (f16)p7;
            *(f16x4*)(sm + LPc + q * 40 + quad * 4)      = lo;  // keys quad*4..+3
            *(f16x4*)(sm + LPc + q * 40 + 16 + quad * 4) = hi;  // keys 16+quad*4..+3
        }

        unsigned long long bm = __ballot(up);
        if (lane == 0) fw[w] = (bm != 0ULL) ? 1 : 0;
        if (quad == 0) aw[w * 16 + l15] = al;

        // ---- single barrier: P/alpha/flags(t) visible; K(t+1)/V(t) landed ----
        asm volatile("s_waitcnt vmcnt(0) lgkmcnt(0)" ::: "memory");
        __builtin_amdgcn_s_barrier();
        __builtin_amdgcn_sched_barrier(0);
    }

    // ---- final PV(63) (buffers at parity of t=63 -> cur=1) ----
    do_pv(LPA + 5120, LVA + 16384,
          (const float*)(sm + LAA + 256), (const int*)(sm + LFA + 16));

    // ---- epilogue: O /= l, store ----
    float* lptr = (float*)(sm + LLL);
    if (quad == 0) lptr[w * 16 + l15] = l_r;
    __syncthreads();
    float linv[16];
#pragma unroll
    for (int r = 0; r < 16; ++r) {
        int row = (r & 3) + ((r >> 2) << 3) + (lhi << 2);
        linv[r] = 1.0f / lptr[qquad * 32 + row];
    }
#pragma unroll
    for (int n = 0; n < 8; ++n) {
#pragma unroll
        for (int r = 0; r < 16; ++r) {
            int row = (r & 3) + ((r >> 2) << 3) + (lhi << 2);
            Y[((size_t)(b * SS + q0 + qquad * 32 + row)) * 512 + dvhalf * 256 + n * 32 + l31] =
                O[n][r] * linv[r];
        }
    }
}

// ---------------------------------------------------------------------------
// Host launcher
// ---------------------------------------------------------------------------
extern "C" void kernel_launch(void* const* d_in, const int* in_sizes, int n_in,
                              void* d_out, int out_size, void* d_ws, size_t ws_size,
                              hipStream_t stream)
{
    const float* x  = (const float*)d_in[0];
    const float* We = (const float*)d_in[1];
    const float* Wk = (const float*)d_in[2];
    const float* Wq = (const float*)d_in[3];
    const float* Wv = (const float*)d_in[4];
    float* out = (float*)d_out;

    const size_t WSZ = 3 * 256 * 512;          // 393216
    const size_t XSZ = (size_t)BB * SS * DIN;  // 8388608
    const size_t MSZ = (size_t)BB * SS * 512;  // 16777216

    f16* Wth = (f16*)d_ws;
    f16* Wtl = Wth + WSZ;                      // (unused slot kept for layout)
    f16* Xh  = Wtl + WSZ;
    f16* Xl  = Xh + XSZ;
    f16* Qh  = Xl + XSZ;
    f16* Kh  = Qh + MSZ;
    f16* Vt2 = Kh + MSZ;

    prep_x<<<dim3(XSZ / 4 / 256), dim3(256), 0, stream>>>(x, Xh, Xl);

    fuse_weights<<<dim3(2, 32, 3), dim3(256), 0, stream>>>(We, Wk, Wq, Wv, Wth);

    qkv_gemm<<<dim3(768), dim3(1024), 0, stream>>>(
        Xh, Xl, Wth, Kh, Qh, Vt2);

    attn2<<<dim3(256), dim3(512), 0, stream>>>(Qh, Kh, Vt2, out);
}

// Round 10
// 400.643 us; speedup vs baseline: 2.2046x; 1.0205x over previous
//
#include <hip/hip_runtime.h>
#include <math.h>

// Problem dims (fixed)
#define BB   16
#define SS   2048
#define DIN  256
#define DEMB 512
#define DKQ  512
#define DVV  512

typedef _Float16 f16;
typedef _Float16 half8  __attribute__((ext_vector_type(8)));
typedef _Float16 f16x4  __attribute__((ext_vector_type(4)));
typedef float    f32x4  __attribute__((ext_vector_type(4)));
typedef float    f32x16 __attribute__((ext_vector_type(16)));

#define GLOAD_LDS16(gp, lp)                                                        \
  __builtin_amdgcn_global_load_lds(                                                \
      (const __attribute__((address_space(1))) unsigned int*)(gp),                 \
      (__attribute__((address_space(3))) unsigned int*)(lp), 16, 0, 0)

// V slot permute: decorrelates LDS bank-start across dv rows (2-way max)
__device__ __forceinline__ int vperm(int dv) { return (dv ^ (dv >> 2)) & 3; }

// ---------------------------------------------------------------------------
// Kernel 0: split x (fp32) -> Xh, Xl (fp16 pair, exact to ~2^-22)
// ---------------------------------------------------------------------------
__global__ __launch_bounds__(256) void prep_x(
    const float* __restrict__ x, f16* __restrict__ Xh, f16* __restrict__ Xl)
{
    int idx = blockIdx.x * 256 + threadIdx.x;
    float4 v = ((const float4*)x)[idx];
    f16x4 h, l;
    h.x = (f16)v.x; l.x = (f16)(v.x - (float)h.x);
    h.y = (f16)v.y; l.y = (f16)(v.y - (float)h.y);
    h.z = (f16)v.z; l.z = (f16)(v.z - (float)h.z);
    h.w = (f16)v.w; l.w = (f16)(v.w - (float)h.w);
    ((f16x4*)Xh)[idx] = h;
    ((f16x4*)Xl)[idx] = l;
}

// ---------------------------------------------------------------------------
// Kernel 1: fuse weights W' = W_embed @ W (fp32 math), output TRANSPOSED
// Wth [z][n=512][k=256], f16 high part. Tiled: block = 256 n-cols x 8 m-rows.
// ---------------------------------------------------------------------------
__global__ __launch_bounds__(256) void fuse_weights(
    const float* __restrict__ We, const float* __restrict__ Wk,
    const float* __restrict__ Wq, const float* __restrict__ Wv,
    f16* __restrict__ Wth)
{
    const int n  = blockIdx.x * 256 + threadIdx.x;   // 0..511
    const int m0 = blockIdx.y * 8;                   // 8 m-rows per block
    const int z  = blockIdx.z;
    const float* Wsrc = (z == 0) ? Wk : (z == 1) ? Wq : Wv;

    float acc[8];
#pragma unroll
    for (int j = 0; j < 8; ++j) acc[j] = 0.f;

#pragma unroll 8
    for (int kk = 0; kk < DEMB; ++kk) {
        float wv = Wsrc[kk * 512 + n];
#pragma unroll
        for (int j = 0; j < 8; ++j)
            acc[j] += We[(m0 + j) * DEMB + kk] * wv;
    }
#pragma unroll
    for (int j = 0; j < 8; ++j)
        Wth[(size_t)z * 131072 + n * 256 + m0 + j] = (f16)acc[j];
}

// ---------------------------------------------------------------------------
// Kernel 2 (v7): MFMA projections, 2-term fp16 split (Ah*Bh + Al*Bh).
// A-IN-REGISTERS dataflow; B streams through LDS. R9's fatal bug fixed:
// epilogue scratch is now a DEDICATED wave-private region (16 KB), never
// aliased with the B buffers — the cross-wave race (wave w's scratch region
// was B rows [w*16,+16), read by ALL waves' MFMAs with no barrier) is
// structurally impossible. LDS = 2x32 KB B dbuf + 16 KB scratch = 80 KB
// exactly -> 2 blocks/CU.
// Block = 4 waves x 128 m-rows x one z. Wave holds its 32 A-rows x K=256 in
// VGPRs (128 VGPR; __launch_bounds__(256,2) -> cap 256, no spill). B streams
// in 64-row n-chunks; per chunk: 128 back-to-back MFMAs/wave (full K, no
// k-loop barriers), outputs final -> per-chunk epilogue via private scratch
// (own-wave lgkmcnt only). ONE barrier per chunk.
// B swizzle: LDS[row][s] = B[row][s ^ ((row&7)<<2)]; read slot
// (ks*4+quad) ^ ((l15&7)<<2) — uniform 8 accesses/bank (b128 minimum).
// XCD decode pins each m-panel's batch to the attn2-owning XCD.
//   z=0 -> Kh [row][512]; z=1 -> Qh [row][512] PRE-SCALED by log2(e);
//   z=2 -> Vt2 [b][tile(64)][dv(512)][32 keys], slots permuted by vperm(dv)
// ---------------------------------------------------------------------------
#define BDB 16384    // one B buffer: 64 rows x 256 shorts = 32 KB
#define SCR 32768    // scratch base: 4 waves x 2048 shorts = 16 KB
                     // total 40960 shorts = 80 KB

__global__ __launch_bounds__(256, 2) void qkv_gemm(
    const f16* __restrict__ Xh, const f16* __restrict__ Xl,
    const f16* __restrict__ Wth,
    f16* __restrict__ Kh, f16* __restrict__ Qh, f16* __restrict__ Vt2)
{
    __shared__ __align__(16) short smq[40960];   // 80 KB

    const int tid  = threadIdx.x;
    const int lane = tid & 63;
    const int w    = tid >> 6;                   // 0..3
    const int l15  = lane & 15;
    const int quad = lane >> 4;

    // XCD-pinned decode: xcd owns batches {xcd, xcd+8} (matches attn2).
    const int gid  = blockIdx.x;                 // 0..767
    const int xcd  = gid & 7;
    const int rest = gid >> 3;                   // 0..95
    const int z    = rest % 3;
    const int pl   = rest / 3;                   // 0..31 (m-panels on this xcd)
    const int bb   = xcd + ((pl >> 4) << 3);     // batch
    const int m0   = (bb * 16 + (pl & 15)) * 128;
    const int wm   = w * 32;                     // wave m-base within block

    const f16* Bh = Wth + (size_t)z * 131072;

    // ---- A into registers: rows m0+wm .. +32, full K=256 (once, ever) ----
    half8 ahr[2][8], alr[2][8];
#pragma unroll
    for (int mi = 0; mi < 2; ++mi) {
        const half8* pah = (const half8*)(Xh + (size_t)(m0 + wm + mi * 16 + l15) * 256);
        const half8* pal = (const half8*)(Xl + (size_t)(m0 + wm + mi * 16 + l15) * 256);
#pragma unroll
        for (int ks = 0; ks < 8; ++ks) {
            ahr[mi][ks] = pah[ks * 4 + quad];
            alr[mi][ks] = pal[ks * 4 + quad];
        }
    }

    // ---- B staging: chunk c = n-rows [c*64, +64), 32 KB; 8 instrs/wave ----
    auto stageB = [&](int c, int buf) {
        const int rb = w * 16;                   // wave's 16 rows within chunk
#pragma unroll
        for (int i = 0; i < 8; ++i) {
            int rloc = rb + i * 2 + (lane >> 5);             // row in chunk
            int sl   = (lane & 31) ^ ((rloc & 7) << 2);      // pre-swizzled slot
            GLOAD_LDS16(Bh + (size_t)(c * 64 + rloc) * 256 + sl * 8,
                        smq + buf + (rb + i * 2) * 256);
        }
    };

    stageB(0, 0);
    asm volatile("s_waitcnt vmcnt(0)" ::: "memory");
    __builtin_amdgcn_s_barrier();
    __builtin_amdgcn_sched_barrier(0);

    short* scr = smq + SCR + w * 2048;           // wave-private 4 KB scratch

    for (int c = 0; c < 8; ++c) {
        const int bufc = (c & 1) * BDB;
        const int bufn = ((c + 1) & 1) * BDB;

        if (c < 7) stageB(c + 1, bufn);          // consumed NEXT interval

        __builtin_amdgcn_s_setprio(1);
        f32x4 acc[2][4];
#pragma unroll
        for (int mi = 0; mi < 2; ++mi)
#pragma unroll
            for (int ni = 0; ni < 4; ++ni) acc[mi][ni] = (f32x4){0.f, 0.f, 0.f, 0.f};

#pragma unroll
        for (int ks = 0; ks < 8; ++ks) {
#pragma unroll
            for (int ni = 0; ni < 4; ++ni) {
                half8 bh = *(const half8*)(smq + bufc + (ni * 16 + l15) * 256 +
                                           (((ks * 4 + quad) ^ ((l15 & 7) << 2)) * 8));
#pragma unroll
                for (int mi = 0; mi < 2; ++mi) {
                    acc[mi][ni] = __builtin_amdgcn_mfma_f32_16x16x32_f16(ahr[mi][ks], bh, acc[mi][ni], 0, 0, 0);
                    acc[mi][ni] = __builtin_amdgcn_mfma_f32_16x16x32_f16(alr[mi][ks], bh, acc[mi][ni], 0, 0, 0);
                }
            }
        }
        __builtin_amdgcn_s_setprio(0);

        // ---- per-chunk epilogue via DEDICATED wave-private scratch ----
        const int n0c = c * 64;
        if (z < 2) {
            // scratch [m 32][n 64], stride 64 shorts
            const float qsc = (z == 1) ? 1.44269504f : 1.0f;
#pragma unroll
            for (int mi = 0; mi < 2; ++mi)
#pragma unroll
                for (int ni = 0; ni < 4; ++ni)
#pragma unroll
                    for (int rr = 0; rr < 4; ++rr)
                        *(f16*)(scr + (mi * 16 + quad * 4 + rr) * 64 + ni * 16 + l15) =
                            (f16)(acc[mi][ni][rr] * qsc);
            asm volatile("s_waitcnt lgkmcnt(0)" ::: "memory");
            __builtin_amdgcn_sched_barrier(0);
            f16* Out = (z == 0) ? Kh : Qh;
            const int g8 = lane & 7;             // 16B col-group
#pragma unroll
            for (int j = 0; j < 4; ++j) {
                int mr = j * 8 + (lane >> 3);    // 0..31
                half8 v = *(const half8*)(scr + mr * 64 + g8 * 8);
                *(half8*)&Out[(size_t)(m0 + wm + mr) * 512 + n0c + g8 * 8] = v;
            }
        } else {
            // scratch [dv 64][m 32], stride 32 shorts (transpose for Vt2)
#pragma unroll
            for (int mi = 0; mi < 2; ++mi)
#pragma unroll
                for (int ni = 0; ni < 4; ++ni)
#pragma unroll
                    for (int rr = 0; rr < 4; ++rr)
                        *(f16*)(scr + (ni * 16 + l15) * 32 + mi * 16 + quad * 4 + rr) =
                            (f16)acc[mi][ni][rr];
            asm volatile("s_waitcnt lgkmcnt(0)" ::: "memory");
            __builtin_amdgcn_sched_barrier(0);
            const int tt = ((m0 & 2047) >> 5) + w;   // key tile (wave = 32 keys)
            const int dv = n0c + lane;               // this lane's dv row
#pragma unroll
            for (int g = 0; g < 4; ++g) {
                half8 v = *(const half8*)(scr + lane * 32 + g * 8);
                int s = g ^ vperm(dv);
                *(half8*)&Vt2[(((size_t)bb * 64 + tt) * 512 + dv) * 32 + s * 8] = v;
            }
        }

        asm volatile("s_waitcnt vmcnt(0) lgkmcnt(0)" ::: "memory");
        __builtin_amdgcn_s_barrier();
        __builtin_amdgcn_sched_barrier(0);
    }
}

// ---------------------------------------------------------------------------
// Kernel 3: MFMA flash attention — ONE barrier per tile (R3, verified 222us),
// SWAPPED-OPERAND scores + lane-local softmax. UNCHANGED.
// ---------------------------------------------------------------------------
#define LKA 0        // K buf0: 32 keys x 512 d   = 16384 shorts
#define LKB 16384    // K buf1
#define LVA 32768    // V buf0: 512 dv x 32 keys  = 16384 shorts
#define LVB 49152    // V buf1
#define LPA 65536    // P buf0: 128 q x stride 40 =  5120 shorts
#define LPB 70656    // P buf1
#define LAA 75776    // alpha buf0/buf1: 2 x 128 floats = 512 shorts
#define LLL 76288    // l[128] floats             =   256 shorts
#define LFA 76544    // flags buf0/buf1: 2 x 8 ints = 32 shorts
#define LTOT 76576   // 153152 bytes (< 160 KiB)

#define THR_L2 11.5416f   // defer-max threshold: 8 nats in log2 units

__global__ __launch_bounds__(512, 2) void attn2(
    const f16* __restrict__ Qh, const f16* __restrict__ Kh,
    const f16* __restrict__ Vt2, float* __restrict__ Y)
{
    __shared__ __align__(16) short sm[LTOT];

    const int tid  = threadIdx.x;
    const int lane = tid & 63;
    const int w    = tid >> 6;                    // 0..7
    // XCD-aware decode: xcd = gid&7; b = (gid&7) + 8*(gid>>7); q0 = ((gid>>3)&15)*128
    const int gid  = blockIdx.x;
    const int b    = (gid & 7) + ((gid >> 7) << 3);
    const int q0   = ((gid >> 3) & 15) << 7;
    const int l15  = lane & 15;
    const int quad = lane >> 4;
    const int l31  = lane & 31;
    const int lhi  = lane >> 5;
    const int qquad = w >> 1, dvhalf = w & 1;     // PV mapping: 4 q-quads x 2 dv-halves

    const f16* Khb  = Kh  + (size_t)b * SS * 512;
    const f16* Vt2b = Vt2 + (size_t)b * 64 * 512 * 32;

    // ---- Q fragments (resident): wave w, q rows q0+16w .. +15 ----
    half8 qh[16];
    {
        const half8* qhp = (const half8*)(Qh + ((size_t)(b * SS + q0 + w * 16 + l15)) * 512);
#pragma unroll
        for (int ks = 0; ks < 16; ++ks) qh[ks] = qhp[ks * 4 + quad];
    }

    f32x16 O[8];
#pragma unroll
    for (int n = 0; n < 8; ++n)
#pragma unroll
        for (int r = 0; r < 16; ++r) O[n][r] = 0.f;

    float m_pr = -1e30f;   // running max, log2 domain (per lane's q row)
    float l_r  = 0.f;      // running denom (per lane's q row)

    // 8 waves x 4 instrs = 32 KB per tile for each of K and V
    auto stage_K = [&](int t, int lk) {
        const int kb = t * 32;
#pragma unroll
        for (int i = 0; i < 4; ++i) {
            int key = w * 4 + i;
            const f16* g = Khb + ((size_t)(kb + key)) * 512 + ((lane ^ (key & 15)) << 3);
            GLOAD_LDS16(g, sm + lk + key * 512);
        }
    };
    auto stage_V = [&](int t, int lv) {
        const f16* gbase = Vt2b + (size_t)t * 16384 + lane * 8;
#pragma unroll
        for (int i = 0; i < 4; ++i) {
            int off = (w * 4 + i) * 512;
            GLOAD_LDS16(gbase + off, sm + lv + off);
        }
    };

    // ---- PV(tp): rescale O by alpha(tp) then O += P(tp) * V(tp) ----
    auto do_pv = [&](int LPp, int LVp, const float* ap, const int* fp) {
        if (fp[2 * qquad] | fp[2 * qquad + 1]) {
            float av[16];
#pragma unroll
            for (int r = 0; r < 16; ++r) {
                int row = (r & 3) + ((r >> 2) << 3) + (lhi << 2);
                av[r] = ap[qquad * 32 + row];
            }
#pragma unroll
            for (int n = 0; n < 8; ++n)
#pragma unroll
                for (int r = 0; r < 16; ++r) O[n][r] *= av[r];
        }
        half8 pA[2];
#pragma unroll
        for (int ks = 0; ks < 2; ++ks) {
            int q  = qquad * 32 + l31;
            int uk = ks * 2 + lhi;
            pA[ks] = *(const half8*)(sm + LPp + q * 40 + uk * 8);
        }
#pragma unroll
        for (int ks = 0; ks < 2; ++ks) {
#pragma unroll
            for (int n = 0; n < 8; ++n) {
                int dv = dvhalf * 256 + n * 32 + l31;
                int uk = ks * 2 + lhi;
                half8 bf = *(const half8*)(sm + LVp + dv * 32 + ((uk ^ vperm(dv)) << 3));
                O[n] = __builtin_amdgcn_mfma_f32_32x32x16_f16(pA[ks], bf, O[n], 0, 0, 0);
            }
        }
    };

    // ---- prologue: stage K(0) into buf0, sync ----
    stage_K(0, LKA);
    asm volatile("s_waitcnt vmcnt(0)" ::: "memory");
    __builtin_amdgcn_s_barrier();
    __builtin_amdgcn_sched_barrier(0);

    for (int t = 0; t < 64; ++t) {
        const int cur = t & 1;
        const int prv = cur ^ 1;
        const int LKc = LKA + cur * 16384;   // K(t)
        const int LKn = LKA + prv * 16384;   // K(t+1) dest
        const int LVc = LVA + cur * 16384;   // V(t) dest
        const int LVp = LVA + prv * 16384;   // V(t-1)
        const int LPc = LPA + cur * 5120;    // P(t) dest
        const int LPp = LPA + prv * 5120;    // P(t-1)
        float* aw = (float*)(sm + LAA + cur * 256);
        const float* ap = (const float*)(sm + LAA + prv * 256);
        int* fw = (int*)(sm + LFA + cur * 16);
        const int* fp = (const int*)(sm + LFA + prv * 16);

        // prefetch: K(t+1) and V(t); both consumed NEXT interval
        if (t + 1 < 64) stage_K(t + 1, LKn);
        stage_V(t, LVc);

        __builtin_amdgcn_s_setprio(1);
        // ---- PV(t-1) ----
        if (t > 0) do_pv(LPp, LVp, ap, fp);

        // ---- scores(t), SWAPPED: S^T = K * Q^T (16x16x32) ----
        f32x4 S[2];
        S[0] = (f32x4){0.f, 0.f, 0.f, 0.f};
        S[1] = (f32x4){0.f, 0.f, 0.f, 0.f};
#pragma unroll
        for (int ks = 0; ks < 16; ++ks) {
#pragma unroll
            for (int n = 0; n < 2; ++n) {
                int key = n * 16 + l15;
                int ud  = ks * 4 + quad;
                half8 bf = *(const half8*)(sm + LKc + key * 512 + ((ud ^ l15) << 3));
                S[n] = __builtin_amdgcn_mfma_f32_16x16x32_f16(bf, qh[ks], S[n], 0, 0, 0);
            }
        }
        __builtin_amdgcn_s_setprio(0);

        // ---- lane-local online softmax (log2 domain), defer-max ----
        float mx = fmaxf(fmaxf(fmaxf(S[0][0], S[0][1]), fmaxf(S[0][2], S[0][3])),
                         fmaxf(fmaxf(S[1][0], S[1][1]), fmaxf(S[1][2], S[1][3])));
        mx = fmaxf(mx, __shfl_xor(mx, 16, 64));
        mx = fmaxf(mx, __shfl_xor(mx, 32, 64));
        bool up  = mx > m_pr + THR_L2;          // defer small max growth
        float mn = up ? mx : m_pr;
        float al = up ? __builtin_amdgcn_exp2f(m_pr - mn) : 1.0f;
        m_pr = mn;

        float p0 = __builtin_amdgcn_exp2f(S[0][0] - mn);
        float p1 = __builtin_amdgcn_exp2f(S[0][1] - mn);
        float p2 = __builtin_amdgcn_exp2f(S[0][2] - mn);
        float p3 = __builtin_amdgcn_exp2f(S[0][3] - mn);
        float p4 = __builtin_amdgcn_exp2f(S[1][0] - mn);
        float p5 = __builtin_amdgcn_exp2f(S[1][1] - mn);
        float p6 = __builtin_amdgcn_exp2f(S[1][2] - mn);
        float p7 = __builtin_amdgcn_exp2f(S[1][3] - mn);
        float sum = ((p0 + p1) + (p2 + p3)) + ((p4 + p5) + (p6 + p7));
        sum += __shfl_xor(sum, 16, 64);
        sum += __shfl_xor(sum, 32, 64);
        l_r = l_r * al + sum;

        {
            int q = w * 16 + l15;
            f16x4 lo, hi;
            lo.x = (f16)p0; lo.y = (f16)p1; lo.z = (f16)p2; lo.w = (f16)p3;
            hi.x = (f16)p4; hi.y = (f16)p5; hi.z = (f16)p6; hi.w = (f16)p7;
            *(f16x4*)(sm + LPc + q * 40 + quad * 4)      = lo;  // keys quad*4..+3
            *(f16x4*)(sm + LPc + q * 40 + 16 + quad * 4) = hi;  // keys 16+quad*4..+3
        }

        unsigned long long bm = __ballot(up);
        if (lane == 0) fw[w] = (bm != 0ULL) ? 1 : 0;
        if (quad == 0) aw[w * 16 + l15] = al;

        // ---- single barrier: P/alpha/flags(t) visible; K(t+1)/V(t) landed ----
        asm volatile("s_waitcnt vmcnt(0) lgkmcnt(0)" ::: "memory");
        __builtin_amdgcn_s_barrier();
        __builtin_amdgcn_sched_barrier(0);
    }

    // ---- final PV(63) (buffers at parity of t=63 -> cur=1) ----
    do_pv(LPA + 5120, LVA + 16384,
          (const float*)(sm + LAA + 256), (const int*)(sm + LFA + 16));

    // ---- epilogue: O /= l, store ----
    float* lptr = (float*)(sm + LLL);
    if (quad == 0) lptr[w * 16 + l15] = l_r;
    __syncthreads();
    float linv[16];
#pragma unroll
    for (int r = 0; r < 16; ++r) {
        int row = (r & 3) + ((r >> 2) << 3) + (lhi << 2);
        linv[r] = 1.0f / lptr[qquad * 32 + row];
    }
#pragma unroll
    for (int n = 0; n < 8; ++n) {
#pragma unroll
        for (int r = 0; r < 16; ++r) {
            int row = (r & 3) + ((r >> 2) << 3) + (lhi << 2);
            Y[((size_t)(b * SS + q0 + qquad * 32 + row)) * 512 + dvhalf * 256 + n * 32 + l31] =
                O[n][r] * linv[r];
        }
    }
}

// ---------------------------------------------------------------------------
// Host launcher
// ---------------------------------------------------------------------------
extern "C" void kernel_launch(void* const* d_in, const int* in_sizes, int n_in,
                              void* d_out, int out_size, void* d_ws, size_t ws_size,
                              hipStream_t stream)
{
    const float* x  = (const float*)d_in[0];
    const float* We = (const float*)d_in[1];
    const float* Wk = (const float*)d_in[2];
    const float* Wq = (const float*)d_in[3];
    const float* Wv = (const float*)d_in[4];
    float* out = (float*)d_out;

    const size_t WSZ = 3 * 256 * 512;          // 393216
    const size_t XSZ = (size_t)BB * SS * DIN;  // 8388608
    const size_t MSZ = (size_t)BB * SS * 512;  // 16777216

    f16* Wth = (f16*)d_ws;
    f16* Wtl = Wth + WSZ;                      // (unused slot kept for layout)
    f16* Xh  = Wtl + WSZ;
    f16* Xl  = Xh + XSZ;
    f16* Qh  = Xl + XSZ;
    f16* Kh  = Qh + MSZ;
    f16* Vt2 = Kh + MSZ;

    prep_x<<<dim3(XSZ / 4 / 256), dim3(256), 0, stream>>>(x, Xh, Xl);

    fuse_weights<<<dim3(2, 32, 3), dim3(256), 0, stream>>>(We, Wk, Wq, Wv, Wth);

    qkv_gemm<<<dim3(768), dim3(256), 0, stream>>>(
        Xh, Xl, Wth, Kh, Qh, Vt2);

    attn2<<<dim3(256), dim3(512), 0, stream>>>(Qh, Kh, Vt2, out);
}

// Round 11
// 385.521 us; speedup vs baseline: 2.2911x; 1.0392x over previous
//
#include <hip/hip_runtime.h>
#include <math.h>

// Problem dims (fixed)
#define BB   16
#define SS   2048
#define DIN  256
#define DEMB 512
#define DKQ  512
#define DVV  512

typedef _Float16 f16;
typedef _Float16 half8  __attribute__((ext_vector_type(8)));
typedef _Float16 f16x4  __attribute__((ext_vector_type(4)));
typedef float    f32x4  __attribute__((ext_vector_type(4)));
typedef float    f32x16 __attribute__((ext_vector_type(16)));

#define GLOAD_LDS16(gp, lp)                                                        \
  __builtin_amdgcn_global_load_lds(                                                \
      (const __attribute__((address_space(1))) unsigned int*)(gp),                 \
      (__attribute__((address_space(3))) unsigned int*)(lp), 16, 0, 0)

// V slot permute: decorrelates LDS bank-start across dv rows (2-way max)
__device__ __forceinline__ int vperm(int dv) { return (dv ^ (dv >> 2)) & 3; }

// ---------------------------------------------------------------------------
// Kernel 1: fuse weights W' = W_embed @ W (fp32 math), output TRANSPOSED
// Wth [z][n=512][k=256], f16 high part. Tiled: block = 256 n-cols x 8 m-rows.
// ---------------------------------------------------------------------------
__global__ __launch_bounds__(256) void fuse_weights(
    const float* __restrict__ We, const float* __restrict__ Wk,
    const float* __restrict__ Wq, const float* __restrict__ Wv,
    f16* __restrict__ Wth)
{
    const int n  = blockIdx.x * 256 + threadIdx.x;   // 0..511
    const int m0 = blockIdx.y * 8;                   // 8 m-rows per block
    const int z  = blockIdx.z;
    const float* Wsrc = (z == 0) ? Wk : (z == 1) ? Wq : Wv;

    float acc[8];
#pragma unroll
    for (int j = 0; j < 8; ++j) acc[j] = 0.f;

#pragma unroll 8
    for (int kk = 0; kk < DEMB; ++kk) {
        float wv = Wsrc[kk * 512 + n];
#pragma unroll
        for (int j = 0; j < 8; ++j)
            acc[j] += We[(m0 + j) * DEMB + kk] * wv;
    }
#pragma unroll
    for (int j = 0; j < 8; ++j)
        Wth[(size_t)z * 131072 + n * 256 + m0 + j] = (f16)acc[j];
}

// ---------------------------------------------------------------------------
// Kernel 2 (v8): MFMA projections, 2-term fp16 split (Ah*Bh + Al*Bh).
// prep_x MERGED IN: A-panel loaded directly from fp32 x (2x float4 per
// fragment), h/l split done in registers — numerically identical to the old
// prep_x path, but eliminates one dispatch + 100 MB of Xh/Xl HBM round-trip.
// A-IN-REGISTERS dataflow otherwise identical to R10's verified v7:
// Block = 4 waves x 128 m-rows x one z; wave holds 32 A-rows x K=256 in
// VGPRs (128 VGPR; __launch_bounds__(256,2) -> no spill). B streams through
// LDS in 64-row n-chunks, dbuf 2x32 KB; dedicated 16 KB wave-private scratch
// (NO aliasing with B buffers — R9 race fix); 80 KB LDS -> 2 blocks/CU.
// Per chunk: 128 back-to-back MFMAs/wave, per-chunk fused epilogue,
// ONE barrier per chunk. B swizzle: LDS[row][s] = B[row][s^((row&7)<<2)];
// read slot (ks*4+quad)^((l15&7)<<2). XCD decode pins batches {xcd, xcd+8}
// to the attn2-owning XCD.
//   z=0 -> Kh [row][512]; z=1 -> Qh [row][512] PRE-SCALED by log2(e);
//   z=2 -> Vt2 [b][tile(64)][dv(512)][32 keys], slots permuted by vperm(dv)
// ---------------------------------------------------------------------------
#define BDB 16384    // one B buffer: 64 rows x 256 shorts = 32 KB
#define SCR 32768    // scratch base: 4 waves x 2048 shorts = 16 KB
                     // total 40960 shorts = 80 KB

__global__ __launch_bounds__(256, 2) void qkv_gemm(
    const float* __restrict__ x,
    const f16* __restrict__ Wth,
    f16* __restrict__ Kh, f16* __restrict__ Qh, f16* __restrict__ Vt2)
{
    __shared__ __align__(16) short smq[40960];   // 80 KB

    const int tid  = threadIdx.x;
    const int lane = tid & 63;
    const int w    = tid >> 6;                   // 0..3
    const int l15  = lane & 15;
    const int quad = lane >> 4;

    // XCD-pinned decode: xcd owns batches {xcd, xcd+8} (matches attn2).
    const int gid  = blockIdx.x;                 // 0..767
    const int xcd  = gid & 7;
    const int rest = gid >> 3;                   // 0..95
    const int z    = rest % 3;
    const int pl   = rest / 3;                   // 0..31 (m-panels on this xcd)
    const int bb   = xcd + ((pl >> 4) << 3);     // batch
    const int m0   = (bb * 16 + (pl & 15)) * 128;
    const int wm   = w * 32;                     // wave m-base within block

    const f16* Bh = Wth + (size_t)z * 131072;

    // ---- A into registers DIRECT from fp32 x, in-register h/l split ----
    half8 ahr[2][8], alr[2][8];
#pragma unroll
    for (int mi = 0; mi < 2; ++mi) {
        const float* px = x + (size_t)(m0 + wm + mi * 16 + l15) * 256;
#pragma unroll
        for (int ks = 0; ks < 8; ++ks) {
            const float* pk = px + ks * 32 + quad * 8;
            float4 v0 = *(const float4*)(pk);
            float4 v1 = *(const float4*)(pk + 4);
            half8 h, l;
            h[0] = (f16)v0.x; l[0] = (f16)(v0.x - (float)h[0]);
            h[1] = (f16)v0.y; l[1] = (f16)(v0.y - (float)h[1]);
            h[2] = (f16)v0.z; l[2] = (f16)(v0.z - (float)h[2]);
            h[3] = (f16)v0.w; l[3] = (f16)(v0.w - (float)h[3]);
            h[4] = (f16)v1.x; l[4] = (f16)(v1.x - (float)h[4]);
            h[5] = (f16)v1.y; l[5] = (f16)(v1.y - (float)h[5]);
            h[6] = (f16)v1.z; l[6] = (f16)(v1.z - (float)h[6]);
            h[7] = (f16)v1.w; l[7] = (f16)(v1.w - (float)h[7]);
            ahr[mi][ks] = h;
            alr[mi][ks] = l;
        }
    }

    // ---- B staging: chunk c = n-rows [c*64, +64), 32 KB; 8 instrs/wave ----
    auto stageB = [&](int c, int buf) {
        const int rb = w * 16;                   // wave's 16 rows within chunk
#pragma unroll
        for (int i = 0; i < 8; ++i) {
            int rloc = rb + i * 2 + (lane >> 5);             // row in chunk
            int sl   = (lane & 31) ^ ((rloc & 7) << 2);      // pre-swizzled slot
            GLOAD_LDS16(Bh + (size_t)(c * 64 + rloc) * 256 + sl * 8,
                        smq + buf + (rb + i * 2) * 256);
        }
    };

    stageB(0, 0);
    asm volatile("s_waitcnt vmcnt(0)" ::: "memory");
    __builtin_amdgcn_s_barrier();
    __builtin_amdgcn_sched_barrier(0);

    short* scr = smq + SCR + w * 2048;           // wave-private 4 KB scratch

    for (int c = 0; c < 8; ++c) {
        const int bufc = (c & 1) * BDB;
        const int bufn = ((c + 1) & 1) * BDB;

        if (c < 7) stageB(c + 1, bufn);          // consumed NEXT interval

        __builtin_amdgcn_s_setprio(1);
        f32x4 acc[2][4];
#pragma unroll
        for (int mi = 0; mi < 2; ++mi)
#pragma unroll
            for (int ni = 0; ni < 4; ++ni) acc[mi][ni] = (f32x4){0.f, 0.f, 0.f, 0.f};

#pragma unroll
        for (int ks = 0; ks < 8; ++ks) {
#pragma unroll
            for (int ni = 0; ni < 4; ++ni) {
                half8 bh = *(const half8*)(smq + bufc + (ni * 16 + l15) * 256 +
                                           (((ks * 4 + quad) ^ ((l15 & 7) << 2)) * 8));
#pragma unroll
                for (int mi = 0; mi < 2; ++mi) {
                    acc[mi][ni] = __builtin_amdgcn_mfma_f32_16x16x32_f16(ahr[mi][ks], bh, acc[mi][ni], 0, 0, 0);
                    acc[mi][ni] = __builtin_amdgcn_mfma_f32_16x16x32_f16(alr[mi][ks], bh, acc[mi][ni], 0, 0, 0);
                }
            }
        }
        __builtin_amdgcn_s_setprio(0);

        // ---- per-chunk epilogue via DEDICATED wave-private scratch ----
        const int n0c = c * 64;
        if (z < 2) {
            // scratch [m 32][n 64], stride 64 shorts
            const float qsc = (z == 1) ? 1.44269504f : 1.0f;
#pragma unroll
            for (int mi = 0; mi < 2; ++mi)
#pragma unroll
                for (int ni = 0; ni < 4; ++ni)
#pragma unroll
                    for (int rr = 0; rr < 4; ++rr)
                        *(f16*)(scr + (mi * 16 + quad * 4 + rr) * 64 + ni * 16 + l15) =
                            (f16)(acc[mi][ni][rr] * qsc);
            asm volatile("s_waitcnt lgkmcnt(0)" ::: "memory");
            __builtin_amdgcn_sched_barrier(0);
            f16* Out = (z == 0) ? Kh : Qh;
            const int g8 = lane & 7;             // 16B col-group
#pragma unroll
            for (int j = 0; j < 4; ++j) {
                int mr = j * 8 + (lane >> 3);    // 0..31
                half8 v = *(const half8*)(scr + mr * 64 + g8 * 8);
                *(half8*)&Out[(size_t)(m0 + wm + mr) * 512 + n0c + g8 * 8] = v;
            }
        } else {
            // scratch [dv 64][m 32], stride 32 shorts (transpose for Vt2)
#pragma unroll
            for (int mi = 0; mi < 2; ++mi)
#pragma unroll
                for (int ni = 0; ni < 4; ++ni)
#pragma unroll
                    for (int rr = 0; rr < 4; ++rr)
                        *(f16*)(scr + (ni * 16 + l15) * 32 + mi * 16 + quad * 4 + rr) =
                            (f16)acc[mi][ni][rr];
            asm volatile("s_waitcnt lgkmcnt(0)" ::: "memory");
            __builtin_amdgcn_sched_barrier(0);
            const int tt = ((m0 & 2047) >> 5) + w;   // key tile (wave = 32 keys)
            const int dv = n0c + lane;               // this lane's dv row
#pragma unroll
            for (int g = 0; g < 4; ++g) {
                half8 v = *(const half8*)(scr + lane * 32 + g * 8);
                int s = g ^ vperm(dv);
                *(half8*)&Vt2[(((size_t)bb * 64 + tt) * 512 + dv) * 32 + s * 8] = v;
            }
        }

        asm volatile("s_waitcnt vmcnt(0) lgkmcnt(0)" ::: "memory");
        __builtin_amdgcn_s_barrier();
        __builtin_amdgcn_sched_barrier(0);
    }
}

// ---------------------------------------------------------------------------
// Kernel 3: MFMA flash attention — ONE barrier per tile (R3, verified 222us),
// SWAPPED-OPERAND scores + lane-local softmax. UNCHANGED.
// ---------------------------------------------------------------------------
#define LKA 0        // K buf0: 32 keys x 512 d   = 16384 shorts
#define LKB 16384    // K buf1
#define LVA 32768    // V buf0: 512 dv x 32 keys  = 16384 shorts
#define LVB 49152    // V buf1
#define LPA 65536    // P buf0: 128 q x stride 40 =  5120 shorts
#define LPB 70656    // P buf1
#define LAA 75776    // alpha buf0/buf1: 2 x 128 floats = 512 shorts
#define LLL 76288    // l[128] floats             =   256 shorts
#define LFA 76544    // flags buf0/buf1: 2 x 8 ints = 32 shorts
#define LTOT 76576   // 153152 bytes (< 160 KiB)

#define THR_L2 11.5416f   // defer-max threshold: 8 nats in log2 units

__global__ __launch_bounds__(512, 2) void attn2(
    const f16* __restrict__ Qh, const f16* __restrict__ Kh,
    const f16* __restrict__ Vt2, float* __restrict__ Y)
{
    __shared__ __align__(16) short sm[LTOT];

    const int tid  = threadIdx.x;
    const int lane = tid & 63;
    const int w    = tid >> 6;                    // 0..7
    // XCD-aware decode: xcd = gid&7; b = (gid&7) + 8*(gid>>7); q0 = ((gid>>3)&15)*128
    const int gid  = blockIdx.x;
    const int b    = (gid & 7) + ((gid >> 7) << 3);
    const int q0   = ((gid >> 3) & 15) << 7;
    const int l15  = lane & 15;
    const int quad = lane >> 4;
    const int l31  = lane & 31;
    const int lhi  = lane >> 5;
    const int qquad = w >> 1, dvhalf = w & 1;     // PV mapping: 4 q-quads x 2 dv-halves

    const f16* Khb  = Kh  + (size_t)b * SS * 512;
    const f16* Vt2b = Vt2 + (size_t)b * 64 * 512 * 32;

    // ---- Q fragments (resident): wave w, q rows q0+16w .. +15 ----
    half8 qh[16];
    {
        const half8* qhp = (const half8*)(Qh + ((size_t)(b * SS + q0 + w * 16 + l15)) * 512);
#pragma unroll
        for (int ks = 0; ks < 16; ++ks) qh[ks] = qhp[ks * 4 + quad];
    }

    f32x16 O[8];
#pragma unroll
    for (int n = 0; n < 8; ++n)
#pragma unroll
        for (int r = 0; r < 16; ++r) O[n][r] = 0.f;

    float m_pr = -1e30f;   // running max, log2 domain (per lane's q row)
    float l_r  = 0.f;      // running denom (per lane's q row)

    // 8 waves x 4 instrs = 32 KB per tile for each of K and V
    auto stage_K = [&](int t, int lk) {
        const int kb = t * 32;
#pragma unroll
        for (int i = 0; i < 4; ++i) {
            int key = w * 4 + i;
            const f16* g = Khb + ((size_t)(kb + key)) * 512 + ((lane ^ (key & 15)) << 3);
            GLOAD_LDS16(g, sm + lk + key * 512);
        }
    };
    auto stage_V = [&](int t, int lv) {
        const f16* gbase = Vt2b + (size_t)t * 16384 + lane * 8;
#pragma unroll
        for (int i = 0; i < 4; ++i) {
            int off = (w * 4 + i) * 512;
            GLOAD_LDS16(gbase + off, sm + lv + off);
        }
    };

    // ---- PV(tp): rescale O by alpha(tp) then O += P(tp) * V(tp) ----
    auto do_pv = [&](int LPp, int LVp, const float* ap, const int* fp) {
        if (fp[2 * qquad] | fp[2 * qquad + 1]) {
            float av[16];
#pragma unroll
            for (int r = 0; r < 16; ++r) {
                int row = (r & 3) + ((r >> 2) << 3) + (lhi << 2);
                av[r] = ap[qquad * 32 + row];
            }
#pragma unroll
            for (int n = 0; n < 8; ++n)
#pragma unroll
                for (int r = 0; r < 16; ++r) O[n][r] *= av[r];
        }
        half8 pA[2];
#pragma unroll
        for (int ks = 0; ks < 2; ++ks) {
            int q  = qquad * 32 + l31;
            int uk = ks * 2 + lhi;
            pA[ks] = *(const half8*)(sm + LPp + q * 40 + uk * 8);
        }
#pragma unroll
        for (int ks = 0; ks < 2; ++ks) {
#pragma unroll
            for (int n = 0; n < 8; ++n) {
                int dv = dvhalf * 256 + n * 32 + l31;
                int uk = ks * 2 + lhi;
                half8 bf = *(const half8*)(sm + LVp + dv * 32 + ((uk ^ vperm(dv)) << 3));
                O[n] = __builtin_amdgcn_mfma_f32_32x32x16_f16(pA[ks], bf, O[n], 0, 0, 0);
            }
        }
    };

    // ---- prologue: stage K(0) into buf0, sync ----
    stage_K(0, LKA);
    asm volatile("s_waitcnt vmcnt(0)" ::: "memory");
    __builtin_amdgcn_s_barrier();
    __builtin_amdgcn_sched_barrier(0);

    for (int t = 0; t < 64; ++t) {
        const int cur = t & 1;
        const int prv = cur ^ 1;
        const int LKc = LKA + cur * 16384;   // K(t)
        const int LKn = LKA + prv * 16384;   // K(t+1) dest
        const int LVc = LVA + cur * 16384;   // V(t) dest
        const int LVp = LVA + prv * 16384;   // V(t-1)
        const int LPc = LPA + cur * 5120;    // P(t) dest
        const int LPp = LPA + prv * 5120;    // P(t-1)
        float* aw = (float*)(sm + LAA + cur * 256);
        const float* ap = (const float*)(sm + LAA + prv * 256);
        int* fw = (int*)(sm + LFA + cur * 16);
        const int* fp = (const int*)(sm + LFA + prv * 16);

        // prefetch: K(t+1) and V(t); both consumed NEXT interval
        if (t + 1 < 64) stage_K(t + 1, LKn);
        stage_V(t, LVc);

        __builtin_amdgcn_s_setprio(1);
        // ---- PV(t-1) ----
        if (t > 0) do_pv(LPp, LVp, ap, fp);

        // ---- scores(t), SWAPPED: S^T = K * Q^T (16x16x32) ----
        f32x4 S[2];
        S[0] = (f32x4){0.f, 0.f, 0.f, 0.f};
        S[1] = (f32x4){0.f, 0.f, 0.f, 0.f};
#pragma unroll
        for (int ks = 0; ks < 16; ++ks) {
#pragma unroll
            for (int n = 0; n < 2; ++n) {
                int key = n * 16 + l15;
                int ud  = ks * 4 + quad;
                half8 bf = *(const half8*)(sm + LKc + key * 512 + ((ud ^ l15) << 3));
                S[n] = __builtin_amdgcn_mfma_f32_16x16x32_f16(bf, qh[ks], S[n], 0, 0, 0);
            }
        }
        __builtin_amdgcn_s_setprio(0);

        // ---- lane-local online softmax (log2 domain), defer-max ----
        float mx = fmaxf(fmaxf(fmaxf(S[0][0], S[0][1]), fmaxf(S[0][2], S[0][3])),
                         fmaxf(fmaxf(S[1][0], S[1][1]), fmaxf(S[1][2], S[1][3])));
        mx = fmaxf(mx, __shfl_xor(mx, 16, 64));
        mx = fmaxf(mx, __shfl_xor(mx, 32, 64));
        bool up  = mx > m_pr + THR_L2;          // defer small max growth
        float mn = up ? mx : m_pr;
        float al = up ? __builtin_amdgcn_exp2f(m_pr - mn) : 1.0f;
        m_pr = mn;

        float p0 = __builtin_amdgcn_exp2f(S[0][0] - mn);
        float p1 = __builtin_amdgcn_exp2f(S[0][1] - mn);
        float p2 = __builtin_amdgcn_exp2f(S[0][2] - mn);
        float p3 = __builtin_amdgcn_exp2f(S[0][3] - mn);
        float p4 = __builtin_amdgcn_exp2f(S[1][0] - mn);
        float p5 = __builtin_amdgcn_exp2f(S[1][1] - mn);
        float p6 = __builtin_amdgcn_exp2f(S[1][2] - mn);
        float p7 = __builtin_amdgcn_exp2f(S[1][3] - mn);
        float sum = ((p0 + p1) + (p2 + p3)) + ((p4 + p5) + (p6 + p7));
        sum += __shfl_xor(sum, 16, 64);
        sum += __shfl_xor(sum, 32, 64);
        l_r = l_r * al + sum;

        {
            int q = w * 16 + l15;
            f16x4 lo, hi;
            lo.x = (f16)p0; lo.y = (f16)p1; lo.z = (f16)p2; lo.w = (f16)p3;
            hi.x = (f16)p4; hi.y = (f16)p5; hi.z = (f16)p6; hi.w = (f16)p7;
            *(f16x4*)(sm + LPc + q * 40 + quad * 4)      = lo;  // keys quad*4..+3
            *(f16x4*)(sm + LPc + q * 40 + 16 + quad * 4) = hi;  // keys 16+quad*4..+3
        }

        unsigned long long bm = __ballot(up);
        if (lane == 0) fw[w] = (bm != 0ULL) ? 1 : 0;
        if (quad == 0) aw[w * 16 + l15] = al;

        // ---- single barrier: P/alpha/flags(t) visible; K(t+1)/V(t) landed ----
        asm volatile("s_waitcnt vmcnt(0) lgkmcnt(0)" ::: "memory");
        __builtin_amdgcn_s_barrier();
        __builtin_amdgcn_sched_barrier(0);
    }

    // ---- final PV(63) (buffers at parity of t=63 -> cur=1) ----
    do_pv(LPA + 5120, LVA + 16384,
          (const float*)(sm + LAA + 256), (const int*)(sm + LFA + 16));

    // ---- epilogue: O /= l, store ----
    float* lptr = (float*)(sm + LLL);
    if (quad == 0) lptr[w * 16 + l15] = l_r;
    __syncthreads();
    float linv[16];
#pragma unroll
    for (int r = 0; r < 16; ++r) {
        int row = (r & 3) + ((r >> 2) << 3) + (lhi << 2);
        linv[r] = 1.0f / lptr[qquad * 32 + row];
    }
#pragma unroll
    for (int n = 0; n < 8; ++n) {
#pragma unroll
        for (int r = 0; r < 16; ++r) {
            int row = (r & 3) + ((r >> 2) << 3) + (lhi << 2);
            Y[((size_t)(b * SS + q0 + qquad * 32 + row)) * 512 + dvhalf * 256 + n * 32 + l31] =
                O[n][r] * linv[r];
        }
    }
}

// ---------------------------------------------------------------------------
// Host launcher
// ---------------------------------------------------------------------------
extern "C" void kernel_launch(void* const* d_in, const int* in_sizes, int n_in,
                              void* d_out, int out_size, void* d_ws, size_t ws_size,
                              hipStream_t stream)
{
    const float* x  = (const float*)d_in[0];
    const float* We = (const float*)d_in[1];
    const float* Wk = (const float*)d_in[2];
    const float* Wq = (const float*)d_in[3];
    const float* Wv = (const float*)d_in[4];
    float* out = (float*)d_out;

    const size_t WSZ = 3 * 256 * 512;          // 393216
    const size_t MSZ = (size_t)BB * SS * 512;  // 16777216

    f16* Wth = (f16*)d_ws;
    f16* Qh  = Wth + WSZ;
    f16* Kh  = Qh + MSZ;
    f16* Vt2 = Kh + MSZ;

    fuse_weights<<<dim3(2, 32, 3), dim3(256), 0, stream>>>(We, Wk, Wq, Wv, Wth);

    qkv_gemm<<<dim3(768), dim3(256), 0, stream>>>(
        x, Wth, Kh, Qh, Vt2);

    attn2<<<dim3(256), dim3(512), 0, stream>>>(Qh, Kh, Vt2, out);
}